// Round 3
// baseline (702.385 us; speedup 1.0000x reference)
//
#include <hip/hip_runtime.h>
#include <hip/hip_bf16.h>
#include <stdint.h>

#define T_TOKENS 4096   // B*S
#define H_DIM    1024
#define F_DIM    4096
#define NE       8
#define NA       8192   // 2*T (total expert assignments)

typedef __bf16 bf16x8 __attribute__((ext_vector_type(8)));
typedef float  f32x4  __attribute__((ext_vector_type(4)));

__device__ __forceinline__ float b2f(unsigned short u) {
    union { float f; uint32_t i; } v; v.i = ((uint32_t)u) << 16; return v.f;
}
__device__ __forceinline__ unsigned short f2b(float f) {
    union { float f; uint32_t i; } v; v.f = f;
    uint32_t x = v.i;
    return (unsigned short)((x + 0x7FFFu + ((x >> 16) & 1u)) >> 16);
}

// ---- dtype probe: flag=1 if inputs are fp32, 0 if bf16 --------------------
// bf16 N(0,1) data: exponent field of each ushort is ~[112,130].
// fp32 data read as ushort pairs: even index = float low half -> bits 14:7
// are uniform mantissa bits -> rarely in range.
__global__ void probe_kernel(const unsigned short* __restrict__ hs,
                             int* __restrict__ flag) {
    int lane = threadIdx.x;  // 64 threads
    int cnt = 0;
    for (int j = 0; j < 16; j++) {
        unsigned short u = hs[(lane * 16 + j) * 2];  // even indices only
        int e = (u >> 7) & 0xFF;
        if (e >= 100 && e <= 135) cnt++;
    }
    for (int off = 32; off > 0; off >>= 1) cnt += __shfl_down(cnt, off);
    if (lane == 0) *flag = (cnt >= 512) ? 0 : 1;  // bf16: ~1024, fp32: ~140
}

// ---- hidden_states -> bf16 ws copy ---------------------------------------
__global__ __launch_bounds__(256) void conv_hs_kernel(
    const void* __restrict__ hs, const int* __restrict__ flag,
    unsigned short* __restrict__ out) {
    size_t idx = ((size_t)blockIdx.x * 256 + threadIdx.x) * 8;
    if (*flag) {
        const float* p = (const float*)hs + idx;
        float4 a = *(const float4*)p, b = *(const float4*)(p + 4);
        ushort4 o0, o1;
        o0.x = f2b(a.x); o0.y = f2b(a.y); o0.z = f2b(a.z); o0.w = f2b(a.w);
        o1.x = f2b(b.x); o1.y = f2b(b.y); o1.z = f2b(b.z); o1.w = f2b(b.w);
        *(ushort4*)(out + idx) = o0;
        *(ushort4*)(out + idx + 4) = o1;
    } else {
        *(uint4*)(out + idx) = *(const uint4*)((const unsigned short*)hs + idx);
    }
}

// ---- router: one wave per token, native-precision dot (tie-break safety) --
__global__ __launch_bounds__(256) void router_kernel(
    const void* __restrict__ hs, const void* __restrict__ rw,
    const void* __restrict__ rb, const int* __restrict__ flag,
    int* __restrict__ top_i, float* __restrict__ top_w) {
    bool f32 = (*flag != 0);
    int wave = threadIdx.x >> 6, lane = threadIdx.x & 63;
    int t = blockIdx.x * 4 + wave;
    float acc[NE];
#pragma unroll
    for (int e = 0; e < NE; e++) acc[e] = 0.f;
    if (f32) {
        const float* hrow = (const float*)hs + (size_t)t * H_DIM;
        const float* rwf = (const float*)rw;
        for (int j = 0; j < 16; j++) {
            int k = j * 64 + lane;
            float h = hrow[k];
            float4 a = *(const float4*)(rwf + (size_t)k * NE);
            float4 b = *(const float4*)(rwf + (size_t)k * NE + 4);
            acc[0] += h * a.x; acc[1] += h * a.y; acc[2] += h * a.z; acc[3] += h * a.w;
            acc[4] += h * b.x; acc[5] += h * b.y; acc[6] += h * b.z; acc[7] += h * b.w;
        }
    } else {
        const unsigned short* hrow = (const unsigned short*)hs + (size_t)t * H_DIM;
        const unsigned short* rwu = (const unsigned short*)rw;
        for (int j = 0; j < 16; j++) {
            int k = j * 64 + lane;
            float h = b2f(hrow[k]);
            uint4 rv = *(const uint4*)(rwu + (size_t)k * NE);
            const unsigned short* rs = (const unsigned short*)&rv;
#pragma unroll
            for (int e = 0; e < NE; e++) acc[e] += h * b2f(rs[e]);
        }
    }
#pragma unroll
    for (int e = 0; e < NE; e++)
        for (int off = 32; off > 0; off >>= 1) acc[e] += __shfl_down(acc[e], off);
    if (lane == 0) {
        float lg[NE];
#pragma unroll
        for (int e = 0; e < NE; e++)
            lg[e] = acc[e] + (f32 ? ((const float*)rb)[e]
                                  : b2f(((const unsigned short*)rb)[e]));
        int e0 = 0;
        for (int e = 1; e < NE; e++) if (lg[e] > lg[e0]) e0 = e;
        int e1 = (e0 == 0) ? 1 : 0;
        for (int e = 0; e < NE; e++) if (e != e0 && lg[e] > lg[e1]) e1 = e;
        float w0 = 1.f / (1.f + expf(lg[e1] - lg[e0]));
        top_i[t * 2] = e0; top_i[t * 2 + 1] = e1;
        top_w[t * 2] = w0; top_w[t * 2 + 1] = 1.f - w0;
    }
}

// ---- assignment build: one block ------------------------------------------
__global__ __launch_bounds__(256) void assign_kernel(
    const int* __restrict__ top_i, const float* __restrict__ top_w,
    int* __restrict__ token_list, float* __restrict__ wgt_list,
    int* __restrict__ assign_row, int* __restrict__ counts,
    int* __restrict__ offsets) {
    __shared__ int cnt_s[NE], cur_s[NE];
    int tid = threadIdx.x;
    if (tid < NE) cnt_s[tid] = 0;
    __syncthreads();
    for (int idx = tid; idx < NA; idx += 256) atomicAdd(&cnt_s[top_i[idx]], 1);
    __syncthreads();
    if (tid == 0) {
        int run = 0;
        for (int e = 0; e < NE; e++) {
            offsets[e] = run; counts[e] = cnt_s[e]; cur_s[e] = run; run += cnt_s[e];
        }
    }
    __syncthreads();
    for (int idx = tid; idx < NA; idx += 256) {
        int e = top_i[idx];
        int pos = atomicAdd(&cur_s[e], 1);
        token_list[pos] = idx >> 1;
        wgt_list[pos] = top_w[idx];
        assign_row[idx] = pos;
    }
}

// ---- 64x64 transpose to bf16 (from fp32 or bf16), per expert slice z ------
__global__ __launch_bounds__(256) void transpose_kernel(
    const void* __restrict__ in, unsigned short* __restrict__ out,
    int R, int C, const int* __restrict__ flag) {
    bool f32 = (*flag != 0);
    size_t zo = (size_t)blockIdx.z * R * C;
    int c0 = blockIdx.x * 64, r0 = blockIdx.y * 64;
    __shared__ unsigned short t[64][65];
    int tx = threadIdx.x & 31, ty = threadIdx.x >> 5;
    if (f32) {
        const float* inf = (const float*)in + zo;
#pragma unroll
        for (int i = 0; i < 8; i++) {
            int r = ty + i * 8;
            float2 v = *(const float2*)&inf[(size_t)(r0 + r) * C + c0 + tx * 2];
            t[r][tx * 2] = f2b(v.x); t[r][tx * 2 + 1] = f2b(v.y);
        }
    } else {
        const unsigned short* inu = (const unsigned short*)in + zo;
#pragma unroll
        for (int i = 0; i < 8; i++) {
            int r = ty + i * 8;
            ushort2 v = *(const ushort2*)&inu[(size_t)(r0 + r) * C + c0 + tx * 2];
            t[r][tx * 2] = v.x; t[r][tx * 2 + 1] = v.y;
        }
    }
    __syncthreads();
#pragma unroll
    for (int i = 0; i < 8; i++) {
        int cc = ty + i * 8;
        ushort2 w; w.x = t[tx * 2][cc]; w.y = t[tx * 2 + 1][cc];
        *(ushort2*)&out[zo + (size_t)(c0 + cc) * R + r0 + tx * 2] = w;
    }
}

// ---- grouped GEMM, 128x128 tile, BK=64, 16x16x32 bf16 MFMA ----------------
// Manual staging (vec load -> ds_write_b128) with XOR-swizzled LDS layout:
// row r, 16B-chunk c stored at byte r*128 + (c^(r&7))*16  (conflict-free frag reads)
// MODE 0: act = gelu(hs_bf16[gathered] @ w1t^T + b1)  -> bf16
// MODE 1: y   = (act @ w2t^T + b2) * slot_wgt         -> bf16
template <int MODE>
__global__ __launch_bounds__(256) void gemm_kernel(
    const unsigned short* __restrict__ Abase,
    const unsigned short* __restrict__ Bt,   // [E][N][K] bf16 transposed weights
    const void* __restrict__ bias,           // [E][N] fp32 or bf16 per flag
    const int* __restrict__ flag,
    const int* __restrict__ token_list, const float* __restrict__ wgt_list,
    const int* __restrict__ counts, const int* __restrict__ offsets,
    unsigned short* __restrict__ act_out, unsigned short* __restrict__ y_out) {
    constexpr int K    = (MODE == 0) ? H_DIM : F_DIM;
    constexpr int NDIM = (MODE == 0) ? F_DIM : H_DIM;
    constexpr int AST  = (MODE == 0) ? H_DIM : F_DIM;

    const int e = blockIdx.z;
    const int cnt = counts[e];
    const int m0 = blockIdx.y * 128;
    if (m0 >= cnt) return;
    const int off = offsets[e];
    const int n0 = blockIdx.x * 128;
    const bool f32 = (*flag != 0);

    __shared__ __bf16 As[128 * 64];
    __shared__ __bf16 Bs[128 * 64];
    __shared__ int   tok_s[128];
    __shared__ float wgt_s[128];

    const int tid = threadIdx.x;
    const int wave = tid >> 6, lane = tid & 63;

    if (tid < 128) {
        int r = off + min(m0 + tid, cnt - 1);
        tok_s[tid] = (MODE == 0) ? token_list[r] : r;
        wgt_s[tid] = wgt_list[r];
    }
    __syncthreads();

    // per-thread staging: 4 A rows + 4 B rows, 16B each
    const int c = tid & 7;        // chunk within 64-elem K-slab
    const int rsub = tid >> 3;    // 0..31
    const unsigned short* Bexp = Bt + (size_t)e * NDIM * K;
    size_t gofsA[4], gofsB[4];
    uint32_t lofs[4];
#pragma unroll
    for (int i = 0; i < 4; i++) {
        int r = i * 32 + rsub;
        int arow = tok_s[r];
        gofsA[i] = (size_t)arow * AST + c * 8;
        gofsB[i] = (size_t)(n0 + r) * K + c * 8;
        lofs[i] = r * 64 + ((c ^ (r & 7)) * 8);
    }

    f32x4 acc[4][4];
#pragma unroll
    for (int i = 0; i < 4; i++)
#pragma unroll
        for (int j = 0; j < 4; j++) acc[i][j] = (f32x4){0.f, 0.f, 0.f, 0.f};

    const int wr = wave >> 1, wc = wave & 1;
    const int lane15 = lane & 15, quad = lane >> 4;

    for (int kt = 0; kt < K / 64; kt++) {
        bf16x8 va[4], vb[4];
#pragma unroll
        for (int i = 0; i < 4; i++)
            va[i] = *(const bf16x8*)(Abase + gofsA[i] + (size_t)kt * 64);
#pragma unroll
        for (int i = 0; i < 4; i++)
            vb[i] = *(const bf16x8*)(Bexp + gofsB[i] + (size_t)kt * 64);
        __syncthreads();  // prev iter's frag reads complete before overwrite
#pragma unroll
        for (int i = 0; i < 4; i++) *(bf16x8*)(As + lofs[i]) = va[i];
#pragma unroll
        for (int i = 0; i < 4; i++) *(bf16x8*)(Bs + lofs[i]) = vb[i];
        __syncthreads();
#pragma unroll
        for (int kk = 0; kk < 2; kk++) {
            bf16x8 a[4], b[4];
#pragma unroll
            for (int i = 0; i < 4; i++) {
                int row = wr * 64 + i * 16 + lane15;
                int koff = (kk * 32 + quad * 8) ^ ((row & 7) * 8);
                a[i] = *(const bf16x8*)&As[row * 64 + koff];
            }
#pragma unroll
            for (int j = 0; j < 4; j++) {
                int row = wc * 64 + j * 16 + lane15;
                int koff = (kk * 32 + quad * 8) ^ ((row & 7) * 8);
                b[j] = *(const bf16x8*)&Bs[row * 64 + koff];
            }
#pragma unroll
            for (int i = 0; i < 4; i++)
#pragma unroll
                for (int j = 0; j < 4; j++)
                    acc[i][j] = __builtin_amdgcn_mfma_f32_16x16x32_bf16(a[i], b[j], acc[i][j], 0, 0, 0);
        }
    }

    // epilogue: C/D layout col=lane&15, row=quad*4+reg
#pragma unroll
    for (int j = 0; j < 4; j++) {
        int col = n0 + wc * 64 + j * 16 + lane15;
        float bv = f32 ? ((const float*)bias)[(size_t)e * NDIM + col]
                       : b2f(((const unsigned short*)bias)[(size_t)e * NDIM + col]);
#pragma unroll
        for (int i = 0; i < 4; i++) {
#pragma unroll
            for (int r = 0; r < 4; r++) {
                int rowl = wr * 64 + i * 16 + quad * 4 + r;
                if (m0 + rowl < cnt) {
                    float v = acc[i][j][r] + bv;
                    if (MODE == 0) {
                        v = 0.5f * v * (1.f + erff(v * 0.70710678118f));  // exact GELU
                        act_out[(size_t)(off + m0 + rowl) * F_DIM + col] = f2b(v);
                    } else {
                        y_out[(size_t)(off + m0 + rowl) * H_DIM + col] = f2b(v * wgt_s[rowl]);
                    }
                }
            }
        }
    }
}

// ---- combine: out[t] = y[slot0] + y[slot1]; write bf16 or fp32 ------------
__global__ __launch_bounds__(256) void combine_kernel(
    const unsigned short* __restrict__ y, const int* __restrict__ assign_row,
    void* __restrict__ out, const int* __restrict__ flag) {
    bool f32 = (*flag != 0);
    int t = blockIdx.x;
    int r0 = assign_row[t * 2], r1 = assign_row[t * 2 + 1];
    ushort4 a = ((const ushort4*)(y + (size_t)r0 * H_DIM))[threadIdx.x];
    ushort4 b = ((const ushort4*)(y + (size_t)r1 * H_DIM))[threadIdx.x];
    float s0 = b2f(a.x) + b2f(b.x), s1 = b2f(a.y) + b2f(b.y);
    float s2 = b2f(a.z) + b2f(b.z), s3 = b2f(a.w) + b2f(b.w);
    if (f32) {
        float4 o = {s0, s1, s2, s3};
        ((float4*)out)[(size_t)t * (H_DIM / 4) + threadIdx.x] = o;
    } else {
        ushort4 o;
        o.x = f2b(s0); o.y = f2b(s1); o.z = f2b(s2); o.w = f2b(s3);
        ((ushort4*)((unsigned short*)out + (size_t)t * H_DIM))[threadIdx.x] = o;
    }
}

extern "C" void kernel_launch(void* const* d_in, const int* in_sizes, int n_in,
                              void* d_out, int out_size, void* d_ws, size_t ws_size,
                              hipStream_t stream) {
    const void* hs = d_in[0];
    const void* rw = d_in[1];
    const void* rb = d_in[2];
    const void* w1 = d_in[3];
    const void* b1 = d_in[4];
    const void* w2 = d_in[5];
    const void* b2 = d_in[6];

    char* ws = (char*)d_ws;
    size_t o = 0;
    auto alloc = [&](size_t bytes) {
        char* p = ws + o; o += (bytes + 255) & ~(size_t)255; return p;
    };
    // single reused transpose buffer: w1t for GEMM1, then w2t for GEMM2
    unsigned short* wt   = (unsigned short*)alloc((size_t)NE * F_DIM * H_DIM * 2);  // 64 MB
    unsigned short* act  = (unsigned short*)alloc((size_t)NA * F_DIM * 2);          // 64 MB
    unsigned short* yb   = (unsigned short*)alloc((size_t)NA * H_DIM * 2);          // 16 MB
    unsigned short* hsb  = (unsigned short*)alloc((size_t)T_TOKENS * H_DIM * 2);    //  8 MB
    int*   top_i      = (int*)alloc(NA * 4);
    float* top_w      = (float*)alloc(NA * 4);
    int*   token_list = (int*)alloc(NA * 4);
    float* wgt_list   = (float*)alloc(NA * 4);
    int*   assign_row = (int*)alloc(NA * 4);
    int*   counts     = (int*)alloc(64);
    int*   offsets    = (int*)alloc(64);
    int*   flag       = (int*)alloc(64);
    (void)ws_size; (void)in_sizes; (void)n_in; (void)out_size;

    probe_kernel<<<1, 64, 0, stream>>>((const unsigned short*)hs, flag);
    conv_hs_kernel<<<T_TOKENS * H_DIM / 2048, 256, 0, stream>>>(hs, flag, hsb);
    router_kernel<<<T_TOKENS / 4, 256, 0, stream>>>(hs, rw, rb, flag, top_i, top_w);
    assign_kernel<<<1, 256, 0, stream>>>(top_i, top_w, token_list, wgt_list,
                                         assign_row, counts, offsets);
    transpose_kernel<<<dim3(F_DIM / 64, H_DIM / 64, NE), 256, 0, stream>>>(
        w1, wt, H_DIM, F_DIM, flag);
    gemm_kernel<0><<<dim3(F_DIM / 128, T_TOKENS / 128, NE), 256, 0, stream>>>(
        hsb, wt, b1, flag, token_list, wgt_list, counts, offsets, act, nullptr);
    transpose_kernel<<<dim3(H_DIM / 64, F_DIM / 64, NE), 256, 0, stream>>>(
        w2, wt, F_DIM, H_DIM, flag);
    gemm_kernel<1><<<dim3(H_DIM / 128, T_TOKENS / 128, NE), 256, 0, stream>>>(
        act, wt, b2, flag, token_list, wgt_list, counts, offsets, nullptr, yb);
    combine_kernel<<<T_TOKENS, 256, 0, stream>>>(yb, assign_row, d_out, flag);
}

// Round 4
// 666.363 us; speedup vs baseline: 1.0541x; 1.0541x over previous
//
#include <hip/hip_runtime.h>
#include <hip/hip_bf16.h>
#include <stdint.h>

#define T_TOKENS 4096   // B*S
#define H_DIM    1024
#define F_DIM    4096
#define NE       8
#define NA       8192   // 2*T (total expert assignments)

typedef __bf16 bf16x8 __attribute__((ext_vector_type(8)));
typedef float  f32x4  __attribute__((ext_vector_type(4)));

__device__ __forceinline__ float b2f(unsigned short u) {
    union { float f; uint32_t i; } v; v.i = ((uint32_t)u) << 16; return v.f;
}
__device__ __forceinline__ unsigned short f2b(float f) {
    union { float f; uint32_t i; } v; v.f = f;
    uint32_t x = v.i;
    return (unsigned short)((x + 0x7FFFu + ((x >> 16) & 1u)) >> 16);
}

// async global->LDS, 16B per lane; LDS dest = wave-uniform base + lane*16.
__device__ __forceinline__ void gl_lds16(const void* g, void* l) {
    __builtin_amdgcn_global_load_lds(
        (const __attribute__((address_space(1))) void*)g,
        (__attribute__((address_space(3))) void*)l,
        16, 0, 0);
}

// ---- dtype probe: flag=1 if inputs are fp32, 0 if bf16 --------------------
__global__ void probe_kernel(const unsigned short* __restrict__ hs,
                             int* __restrict__ flag) {
    int lane = threadIdx.x;  // 64 threads
    int cnt = 0;
    for (int j = 0; j < 16; j++) {
        unsigned short u = hs[(lane * 16 + j) * 2];  // even indices only
        int e = (u >> 7) & 0xFF;
        if (e >= 100 && e <= 135) cnt++;
    }
    for (int off = 32; off > 0; off >>= 1) cnt += __shfl_down(cnt, off);
    if (lane == 0) *flag = (cnt >= 512) ? 0 : 1;  // bf16: ~1024, fp32: ~140
}

// ---- router (one wave per token) + fused hs->bf16 conversion --------------
__global__ __launch_bounds__(256) void router_kernel(
    const void* __restrict__ hs, const void* __restrict__ rw,
    const void* __restrict__ rb, const int* __restrict__ flag,
    int* __restrict__ top_i, float* __restrict__ top_w,
    unsigned short* __restrict__ hsb) {
    bool f32 = (*flag != 0);
    int wave = threadIdx.x >> 6, lane = threadIdx.x & 63;
    int t = blockIdx.x * 4 + wave;
    unsigned short* hout = hsb + (size_t)t * H_DIM;
    float acc[NE];
#pragma unroll
    for (int e = 0; e < NE; e++) acc[e] = 0.f;
    if (f32) {
        const float* hrow = (const float*)hs + (size_t)t * H_DIM;
        const float* rwf = (const float*)rw;
        for (int j = 0; j < 16; j++) {
            int k = j * 64 + lane;
            float h = hrow[k];
            hout[k] = f2b(h);
            float4 a = *(const float4*)(rwf + (size_t)k * NE);
            float4 b = *(const float4*)(rwf + (size_t)k * NE + 4);
            acc[0] += h * a.x; acc[1] += h * a.y; acc[2] += h * a.z; acc[3] += h * a.w;
            acc[4] += h * b.x; acc[5] += h * b.y; acc[6] += h * b.z; acc[7] += h * b.w;
        }
    } else {
        const unsigned short* hrow = (const unsigned short*)hs + (size_t)t * H_DIM;
        const unsigned short* rwu = (const unsigned short*)rw;
        for (int j = 0; j < 16; j++) {
            int k = j * 64 + lane;
            unsigned short hu = hrow[k];
            hout[k] = hu;
            float h = b2f(hu);
            uint4 rv = *(const uint4*)(rwu + (size_t)k * NE);
            const unsigned short* rs = (const unsigned short*)&rv;
#pragma unroll
            for (int e = 0; e < NE; e++) acc[e] += h * b2f(rs[e]);
        }
    }
#pragma unroll
    for (int e = 0; e < NE; e++)
        for (int off = 32; off > 0; off >>= 1) acc[e] += __shfl_down(acc[e], off);
    if (lane == 0) {
        float lg[NE];
#pragma unroll
        for (int e = 0; e < NE; e++)
            lg[e] = acc[e] + (f32 ? ((const float*)rb)[e]
                                  : b2f(((const unsigned short*)rb)[e]));
        int e0 = 0;
        for (int e = 1; e < NE; e++) if (lg[e] > lg[e0]) e0 = e;
        int e1 = (e0 == 0) ? 1 : 0;
        for (int e = 0; e < NE; e++) if (e != e0 && lg[e] > lg[e1]) e1 = e;
        float w0 = 1.f / (1.f + expf(lg[e1] - lg[e0]));
        top_i[t * 2] = e0; top_i[t * 2 + 1] = e1;
        top_w[t * 2] = w0; top_w[t * 2 + 1] = 1.f - w0;
    }
}

// ---- assignment build: one block ------------------------------------------
__global__ __launch_bounds__(256) void assign_kernel(
    const int* __restrict__ top_i, const float* __restrict__ top_w,
    int* __restrict__ token_list, float* __restrict__ wgt_list,
    int* __restrict__ assign_row, int* __restrict__ counts,
    int* __restrict__ offsets) {
    __shared__ int cnt_s[NE], cur_s[NE];
    int tid = threadIdx.x;
    if (tid < NE) cnt_s[tid] = 0;
    __syncthreads();
    for (int idx = tid; idx < NA; idx += 256) atomicAdd(&cnt_s[top_i[idx]], 1);
    __syncthreads();
    if (tid == 0) {
        int run = 0;
        for (int e = 0; e < NE; e++) {
            offsets[e] = run; counts[e] = cnt_s[e]; cur_s[e] = run; run += cnt_s[e];
        }
    }
    __syncthreads();
    for (int idx = tid; idx < NA; idx += 256) {
        int e = top_i[idx];
        int pos = atomicAdd(&cur_s[e], 1);
        token_list[pos] = idx >> 1;
        wgt_list[pos] = top_w[idx];
        assign_row[idx] = pos;
    }
}

// ---- 64x64 transpose to bf16 (from fp32 or bf16), per expert slice z ------
__global__ __launch_bounds__(256) void transpose_kernel(
    const void* __restrict__ in, unsigned short* __restrict__ out,
    int R, int C, const int* __restrict__ flag) {
    bool f32 = (*flag != 0);
    size_t zo = (size_t)blockIdx.z * R * C;
    int c0 = blockIdx.x * 64, r0 = blockIdx.y * 64;
    __shared__ unsigned short t[64][65];
    int tx = threadIdx.x & 31, ty = threadIdx.x >> 5;
    if (f32) {
        const float* inf = (const float*)in + zo;
#pragma unroll
        for (int i = 0; i < 8; i++) {
            int r = ty + i * 8;
            float2 v = *(const float2*)&inf[(size_t)(r0 + r) * C + c0 + tx * 2];
            t[r][tx * 2] = f2b(v.x); t[r][tx * 2 + 1] = f2b(v.y);
        }
    } else {
        const unsigned short* inu = (const unsigned short*)in + zo;
#pragma unroll
        for (int i = 0; i < 8; i++) {
            int r = ty + i * 8;
            ushort2 v = *(const ushort2*)&inu[(size_t)(r0 + r) * C + c0 + tx * 2];
            t[r][tx * 2] = v.x; t[r][tx * 2 + 1] = v.y;
        }
    }
    __syncthreads();
#pragma unroll
    for (int i = 0; i < 8; i++) {
        int cc = ty + i * 8;
        ushort2 w; w.x = t[tx * 2][cc]; w.y = t[tx * 2 + 1][cc];
        *(ushort2*)&out[zo + (size_t)(c0 + cc) * R + r0 + tx * 2] = w;
    }
}

// ---- grouped GEMM, BMx128 tile, BK=64, 16x16x32 bf16 MFMA, async staging --
// LDS layout: row r (128B), 16B chunk c stored at slot c^(r&7) (XOR swizzle,
// applied on the *global* fetch address since gl_lds LDS dest is lane-fixed).
// MODE 0 (BM=128): act = gelu(hsb[gathered] @ w1t^T + b1)  -> bf16
// MODE 1 (BM=64):  y   = (act @ w2t^T + b2) * slot_wgt     -> bf16
template <int MODE>
__global__ __launch_bounds__(256) void gemm_kernel(
    const unsigned short* __restrict__ Abase,
    const unsigned short* __restrict__ Bt,   // [E][N][K] bf16 transposed weights
    const void* __restrict__ bias,           // [E][N] fp32 or bf16 per flag
    const int* __restrict__ flag,
    const int* __restrict__ token_list, const float* __restrict__ wgt_list,
    const int* __restrict__ counts, const int* __restrict__ offsets,
    unsigned short* __restrict__ act_out, unsigned short* __restrict__ y_out) {
    constexpr int K    = (MODE == 0) ? H_DIM : F_DIM;
    constexpr int NDIM = (MODE == 0) ? F_DIM : H_DIM;
    constexpr int AST  = (MODE == 0) ? H_DIM : F_DIM;
    constexpr int BM   = (MODE == 0) ? 128 : 64;
    constexpr int MI   = BM / 32;   // A-frag count per wave (4 or 2)

    const int e = blockIdx.z;
    const int cnt = counts[e];
    const int m0 = blockIdx.y * BM;
    if (m0 >= cnt) return;
    const int off = offsets[e];
    const int n0 = blockIdx.x * 128;
    const bool f32 = (*flag != 0);

    __shared__ __bf16 As[BM * 64];
    __shared__ __bf16 Bs[128 * 64];
    __shared__ int   tok_s[BM];
    __shared__ float wgt_s[BM];

    const int tid = threadIdx.x;
    const int wave = tid >> 6, lane = tid & 63;

    if (tid < BM) {
        int r = off + min(m0 + tid, cnt - 1);
        tok_s[tid] = (MODE == 0) ? token_list[r] : r;
        wgt_s[tid] = wgt_list[r];
    }
    __syncthreads();

    // per-instruction: 8 rows x 8 chunks of 16B; lane -> row lane>>3, slot lane&7,
    // fetches global chunk (lane&7)^(lane>>3)  => LDS slot s holds chunk s^(r&7).
    const char* Abytes = (const char*)Abase;
    const char* Bbytes = (const char*)(Bt + (size_t)e * NDIM * K);
    uint64_t ga[MI], gb[4];
    const int chunk = (lane & 7) ^ ((lane >> 3) & 7);
#pragma unroll
    for (int i = 0; i < MI; i++) {
        int rowA = (wave * MI + i) * 8 + (lane >> 3);
        int arow = tok_s[rowA];
        ga[i] = (uint64_t)(uintptr_t)(Abytes + ((size_t)arow * AST + chunk * 8) * 2);
    }
#pragma unroll
    for (int i = 0; i < 4; i++) {
        int rowB = n0 + (wave * 4 + i) * 8 + (lane >> 3);
        gb[i] = (uint64_t)(uintptr_t)(Bbytes + ((size_t)rowB * K + chunk * 8) * 2);
    }

    f32x4 acc[MI][4];
#pragma unroll
    for (int i = 0; i < MI; i++)
#pragma unroll
        for (int j = 0; j < 4; j++) acc[i][j] = (f32x4){0.f, 0.f, 0.f, 0.f};

    const int wr = wave >> 1, wc = wave & 1;
    const int lane15 = lane & 15, quad = lane >> 4;

    for (int kt = 0; kt < K / 64; kt++) {
#pragma unroll
        for (int i = 0; i < MI; i++) {
            gl_lds16((const void*)(uintptr_t)ga[i], (void*)(As + (wave * MI + i) * 512));
            ga[i] += 128;
        }
#pragma unroll
        for (int i = 0; i < 4; i++) {
            gl_lds16((const void*)(uintptr_t)gb[i], (void*)(Bs + (wave * 4 + i) * 512));
            gb[i] += 128;
        }
        __syncthreads();
#pragma unroll
        for (int kk = 0; kk < 2; kk++) {
            bf16x8 a[MI], b[4];
#pragma unroll
            for (int i = 0; i < MI; i++) {
                int row = wr * (BM / 2) + i * 16 + lane15;
                int koff = (kk * 32 + quad * 8) ^ ((row & 7) * 8);
                a[i] = *(const bf16x8*)&As[row * 64 + koff];
            }
#pragma unroll
            for (int j = 0; j < 4; j++) {
                int row = wc * 64 + j * 16 + lane15;
                int koff = (kk * 32 + quad * 8) ^ ((row & 7) * 8);
                b[j] = *(const bf16x8*)&Bs[row * 64 + koff];
            }
#pragma unroll
            for (int i = 0; i < MI; i++)
#pragma unroll
                for (int j = 0; j < 4; j++)
                    acc[i][j] = __builtin_amdgcn_mfma_f32_16x16x32_bf16(a[i], b[j], acc[i][j], 0, 0, 0);
        }
        __syncthreads();
    }

    // epilogue: C/D layout col=lane&15, row=quad*4+reg
#pragma unroll
    for (int j = 0; j < 4; j++) {
        int col = n0 + wc * 64 + j * 16 + lane15;
        float bv = f32 ? ((const float*)bias)[(size_t)e * NDIM + col]
                       : b2f(((const unsigned short*)bias)[(size_t)e * NDIM + col]);
#pragma unroll
        for (int i = 0; i < MI; i++) {
#pragma unroll
            for (int r = 0; r < 4; r++) {
                int rowl = wr * (BM / 2) + i * 16 + quad * 4 + r;
                if (m0 + rowl < cnt) {
                    float v = acc[i][j][r] + bv;
                    if (MODE == 0) {
                        v = 0.5f * v * (1.f + erff(v * 0.70710678118f));  // exact GELU
                        act_out[(size_t)(off + m0 + rowl) * F_DIM + col] = f2b(v);
                    } else {
                        y_out[(size_t)(off + m0 + rowl) * H_DIM + col] = f2b(v * wgt_s[rowl]);
                    }
                }
            }
        }
    }
}

// ---- combine: out[t] = y[slot0] + y[slot1]; write bf16 or fp32 ------------
__global__ __launch_bounds__(256) void combine_kernel(
    const unsigned short* __restrict__ y, const int* __restrict__ assign_row,
    void* __restrict__ out, const int* __restrict__ flag) {
    bool f32 = (*flag != 0);
    int t = blockIdx.x;
    int r0 = assign_row[t * 2], r1 = assign_row[t * 2 + 1];
    ushort4 a = ((const ushort4*)(y + (size_t)r0 * H_DIM))[threadIdx.x];
    ushort4 b = ((const ushort4*)(y + (size_t)r1 * H_DIM))[threadIdx.x];
    float s0 = b2f(a.x) + b2f(b.x), s1 = b2f(a.y) + b2f(b.y);
    float s2 = b2f(a.z) + b2f(b.z), s3 = b2f(a.w) + b2f(b.w);
    if (f32) {
        float4 o = {s0, s1, s2, s3};
        ((float4*)out)[(size_t)t * (H_DIM / 4) + threadIdx.x] = o;
    } else {
        ushort4 o;
        o.x = f2b(s0); o.y = f2b(s1); o.z = f2b(s2); o.w = f2b(s3);
        ((ushort4*)((unsigned short*)out + (size_t)t * H_DIM))[threadIdx.x] = o;
    }
}

extern "C" void kernel_launch(void* const* d_in, const int* in_sizes, int n_in,
                              void* d_out, int out_size, void* d_ws, size_t ws_size,
                              hipStream_t stream) {
    const void* hs = d_in[0];
    const void* rw = d_in[1];
    const void* rb = d_in[2];
    const void* w1 = d_in[3];
    const void* b1 = d_in[4];
    const void* w2 = d_in[5];
    const void* b2 = d_in[6];

    char* ws = (char*)d_ws;
    size_t o = 0;
    auto alloc = [&](size_t bytes) {
        char* p = ws + o; o += (bytes + 255) & ~(size_t)255; return p;
    };
    unsigned short* wt   = (unsigned short*)alloc((size_t)NE * F_DIM * H_DIM * 2);  // 64 MB (reused)
    unsigned short* act  = (unsigned short*)alloc((size_t)NA * F_DIM * 2);          // 64 MB
    unsigned short* yb   = (unsigned short*)alloc((size_t)NA * H_DIM * 2);          // 16 MB
    unsigned short* hsb  = (unsigned short*)alloc((size_t)T_TOKENS * H_DIM * 2);    //  8 MB
    int*   top_i      = (int*)alloc(NA * 4);
    float* top_w      = (float*)alloc(NA * 4);
    int*   token_list = (int*)alloc(NA * 4);
    float* wgt_list   = (float*)alloc(NA * 4);
    int*   assign_row = (int*)alloc(NA * 4);
    int*   counts     = (int*)alloc(64);
    int*   offsets    = (int*)alloc(64);
    int*   flag       = (int*)alloc(64);
    (void)ws_size; (void)in_sizes; (void)n_in; (void)out_size;

    probe_kernel<<<1, 64, 0, stream>>>((const unsigned short*)hs, flag);
    router_kernel<<<T_TOKENS / 4, 256, 0, stream>>>(hs, rw, rb, flag, top_i, top_w, hsb);
    assign_kernel<<<1, 256, 0, stream>>>(top_i, top_w, token_list, wgt_list,
                                         assign_row, counts, offsets);
    transpose_kernel<<<dim3(F_DIM / 64, H_DIM / 64, NE), 256, 0, stream>>>(
        w1, wt, H_DIM, F_DIM, flag);
    gemm_kernel<0><<<dim3(F_DIM / 128, T_TOKENS / 128, NE), 256, 0, stream>>>(
        hsb, wt, b1, flag, token_list, wgt_list, counts, offsets, act, nullptr);
    transpose_kernel<<<dim3(H_DIM / 64, F_DIM / 64, NE), 256, 0, stream>>>(
        w2, wt, F_DIM, H_DIM, flag);
    gemm_kernel<1><<<dim3(H_DIM / 128, NA / 64, NE), 256, 0, stream>>>(
        act, wt, b2, flag, token_list, wgt_list, counts, offsets, nullptr, yb);
    combine_kernel<<<T_TOKENS, 256, 0, stream>>>(yb, assign_row, d_out, flag);
}

// Round 5
// 653.695 us; speedup vs baseline: 1.0745x; 1.0194x over previous
//
#include <hip/hip_runtime.h>
#include <hip/hip_bf16.h>
#include <stdint.h>

#define T_TOKENS 4096   // B*S
#define H_DIM    1024
#define F_DIM    4096
#define NE       8
#define NA       8192   // 2*T (total expert assignments)

typedef __bf16 bf16x8 __attribute__((ext_vector_type(8)));
typedef float  f32x4  __attribute__((ext_vector_type(4)));

__device__ __forceinline__ float b2f(unsigned short u) {
    union { float f; uint32_t i; } v; v.i = ((uint32_t)u) << 16; return v.f;
}
__device__ __forceinline__ unsigned short f2b(float f) {
    union { float f; uint32_t i; } v; v.f = f;
    uint32_t x = v.i;
    return (unsigned short)((x + 0x7FFFu + ((x >> 16) & 1u)) >> 16);
}

// exact GELU via A&S 7.1.26 erf (max err 1.5e-7), branchless, ~14 VALU + v_exp
__device__ __forceinline__ float gelu_f(float x) {
    float z = fabsf(x) * 0.70710678118f;
    float t = 1.0f / (1.0f + 0.3275911f * z);
    float p = t * (0.254829592f + t * (-0.284496736f +
              t * (1.421413741f + t * (-1.453152027f + t * 1.061405429f))));
    float erf_z = 1.0f - p * __expf(-z * z);
    float sgn_erf = (x >= 0.f) ? erf_z : -erf_z;
    return x * (0.5f + 0.5f * sgn_erf);
}

// async global->LDS, 16B per lane; LDS dest = wave-uniform base + lane*16.
__device__ __forceinline__ void gl_lds16(const void* g, void* l) {
    __builtin_amdgcn_global_load_lds(
        (const __attribute__((address_space(1))) void*)g,
        (__attribute__((address_space(3))) void*)l,
        16, 0, 0);
}

// ---- dtype probe: flag=1 if inputs are fp32, 0 if bf16 --------------------
__global__ void probe_kernel(const unsigned short* __restrict__ hs,
                             int* __restrict__ flag) {
    int lane = threadIdx.x;  // 64 threads
    int cnt = 0;
    for (int j = 0; j < 16; j++) {
        unsigned short u = hs[(lane * 16 + j) * 2];  // even indices only
        int e = (u >> 7) & 0xFF;
        if (e >= 100 && e <= 135) cnt++;
    }
    for (int off = 32; off > 0; off >>= 1) cnt += __shfl_down(cnt, off);
    if (lane == 0) *flag = (cnt >= 512) ? 0 : 1;  // bf16: ~1024, fp32: ~140
}

// ---- router (one wave per token) + fused hs->bf16 conversion --------------
__global__ __launch_bounds__(256) void router_kernel(
    const void* __restrict__ hs, const void* __restrict__ rw,
    const void* __restrict__ rb, const int* __restrict__ flag,
    int* __restrict__ top_i, float* __restrict__ top_w,
    unsigned short* __restrict__ hsb) {
    bool f32 = (*flag != 0);
    int wave = threadIdx.x >> 6, lane = threadIdx.x & 63;
    int t = blockIdx.x * 4 + wave;
    unsigned short* hout = hsb + (size_t)t * H_DIM;
    float acc[NE];
#pragma unroll
    for (int e = 0; e < NE; e++) acc[e] = 0.f;
    if (f32) {
        const float* hrow = (const float*)hs + (size_t)t * H_DIM;
        const float* rwf = (const float*)rw;
        for (int j = 0; j < 16; j++) {
            int k = j * 64 + lane;
            float h = hrow[k];
            hout[k] = f2b(h);
            float4 a = *(const float4*)(rwf + (size_t)k * NE);
            float4 b = *(const float4*)(rwf + (size_t)k * NE + 4);
            acc[0] += h * a.x; acc[1] += h * a.y; acc[2] += h * a.z; acc[3] += h * a.w;
            acc[4] += h * b.x; acc[5] += h * b.y; acc[6] += h * b.z; acc[7] += h * b.w;
        }
    } else {
        const unsigned short* hrow = (const unsigned short*)hs + (size_t)t * H_DIM;
        const unsigned short* rwu = (const unsigned short*)rw;
        for (int j = 0; j < 16; j++) {
            int k = j * 64 + lane;
            unsigned short hu = hrow[k];
            hout[k] = hu;
            float h = b2f(hu);
            uint4 rv = *(const uint4*)(rwu + (size_t)k * NE);
            const unsigned short* rs = (const unsigned short*)&rv;
#pragma unroll
            for (int e = 0; e < NE; e++) acc[e] += h * b2f(rs[e]);
        }
    }
#pragma unroll
    for (int e = 0; e < NE; e++)
        for (int off = 32; off > 0; off >>= 1) acc[e] += __shfl_down(acc[e], off);
    if (lane == 0) {
        float lg[NE];
#pragma unroll
        for (int e = 0; e < NE; e++)
            lg[e] = acc[e] + (f32 ? ((const float*)rb)[e]
                                  : b2f(((const unsigned short*)rb)[e]));
        int e0 = 0;
        for (int e = 1; e < NE; e++) if (lg[e] > lg[e0]) e0 = e;
        int e1 = (e0 == 0) ? 1 : 0;
        for (int e = 0; e < NE; e++) if (e != e0 && lg[e] > lg[e1]) e1 = e;
        float w0 = 1.f / (1.f + expf(lg[e1] - lg[e0]));
        top_i[t * 2] = e0; top_i[t * 2 + 1] = e1;
        top_w[t * 2] = w0; top_w[t * 2 + 1] = 1.f - w0;
    }
}

// ---- assignment build: one block ------------------------------------------
__global__ __launch_bounds__(256) void assign_kernel(
    const int* __restrict__ top_i, const float* __restrict__ top_w,
    int* __restrict__ token_list, float* __restrict__ wgt_list,
    int* __restrict__ assign_row, int* __restrict__ counts,
    int* __restrict__ offsets) {
    __shared__ int cnt_s[NE], cur_s[NE];
    int tid = threadIdx.x;
    if (tid < NE) cnt_s[tid] = 0;
    __syncthreads();
    for (int idx = tid; idx < NA; idx += 256) atomicAdd(&cnt_s[top_i[idx]], 1);
    __syncthreads();
    if (tid == 0) {
        int run = 0;
        for (int e = 0; e < NE; e++) {
            offsets[e] = run; counts[e] = cnt_s[e]; cur_s[e] = run; run += cnt_s[e];
        }
    }
    __syncthreads();
    for (int idx = tid; idx < NA; idx += 256) {
        int e = top_i[idx];
        int pos = atomicAdd(&cur_s[e], 1);
        token_list[pos] = idx >> 1;
        wgt_list[pos] = top_w[idx];
        assign_row[idx] = pos;
    }
}

// ---- 64x64 transpose to bf16 (from fp32 or bf16), per expert slice z ------
__global__ __launch_bounds__(256) void transpose_kernel(
    const void* __restrict__ in, unsigned short* __restrict__ out,
    int R, int C, const int* __restrict__ flag) {
    bool f32 = (*flag != 0);
    size_t zo = (size_t)blockIdx.z * R * C;
    int c0 = blockIdx.x * 64, r0 = blockIdx.y * 64;
    __shared__ unsigned short t[64][65];
    int tx = threadIdx.x & 15, ty = threadIdx.x >> 4;  // 16 col-groups x 16 rows
    if (f32) {
        const float* inf = (const float*)in + zo;
#pragma unroll
        for (int i = 0; i < 4; i++) {
            int r = ty + i * 16;
            float4 v = *(const float4*)&inf[(size_t)(r0 + r) * C + c0 + tx * 4];
            t[r][tx * 4] = f2b(v.x); t[r][tx * 4 + 1] = f2b(v.y);
            t[r][tx * 4 + 2] = f2b(v.z); t[r][tx * 4 + 3] = f2b(v.w);
        }
    } else {
        const unsigned short* inu = (const unsigned short*)in + zo;
#pragma unroll
        for (int i = 0; i < 4; i++) {
            int r = ty + i * 16;
            ushort4 v = *(const ushort4*)&inu[(size_t)(r0 + r) * C + c0 + tx * 4];
            t[r][tx * 4] = v.x; t[r][tx * 4 + 1] = v.y;
            t[r][tx * 4 + 2] = v.z; t[r][tx * 4 + 3] = v.w;
        }
    }
    __syncthreads();
#pragma unroll
    for (int i = 0; i < 4; i++) {
        int cc = ty + i * 16;
        ushort4 w;
        w.x = t[tx * 4][cc]; w.y = t[tx * 4 + 1][cc];
        w.z = t[tx * 4 + 2][cc]; w.w = t[tx * 4 + 3][cc];
        *(ushort4*)&out[zo + (size_t)(c0 + cc) * R + r0 + tx * 4] = w;
    }
}

// ---- grouped GEMM, BMx128 tile, BK=32, double-buffered async staging ------
// LDS row = 32 k-elems (64B = 4 chunks of 16B); row r chunk q at slot q^(r&3).
// Staging lane l -> row l>>2, slot l&3, fetches global chunk (l&3)^((l>>2)&3).
// Pipeline: issue loads for tile k+1 into alt buffer, compute tile k, barrier
// (compiler's vmcnt(0)-before-s_barrier then lands after a full compute phase).
// MODE 0 (BM=128): act = gelu(hsb[gathered] @ w1t^T + b1)  -> bf16
// MODE 1 (BM=64):  y   = (act @ w2t^T + b2) * slot_wgt     -> bf16
template <int MODE>
__global__ __launch_bounds__(256) void gemm_kernel(
    const unsigned short* __restrict__ Abase,
    const unsigned short* __restrict__ Bt,   // [E][N][K] bf16 transposed weights
    const void* __restrict__ bias,           // [E][N] fp32 or bf16 per flag
    const int* __restrict__ flag,
    const int* __restrict__ token_list, const float* __restrict__ wgt_list,
    const int* __restrict__ counts, const int* __restrict__ offsets,
    unsigned short* __restrict__ act_out, unsigned short* __restrict__ y_out) {
    constexpr int K    = (MODE == 0) ? H_DIM : F_DIM;
    constexpr int NDIM = (MODE == 0) ? F_DIM : H_DIM;
    constexpr int AST  = (MODE == 0) ? H_DIM : F_DIM;
    constexpr int BM   = (MODE == 0) ? 128 : 64;
    constexpr int MI   = BM / 32;      // A-frags per wave (4 or 2)
    constexpr int NIA  = BM / 64;      // A staging instrs per wave (2 or 1)
    constexpr int NK   = K / 32;
    constexpr int ABUF = BM * 32;      // elements per A buffer
    constexpr int BBUF = 128 * 32;

    const int e = blockIdx.z;
    const int cnt = counts[e];
    const int m0 = blockIdx.y * BM;
    if (m0 >= cnt) return;
    const int off = offsets[e];
    const int n0 = blockIdx.x * 128;
    const bool f32 = (*flag != 0);

    __shared__ __bf16 As[2 * ABUF];
    __shared__ __bf16 Bs[2 * BBUF];
    __shared__ int   tok_s[BM];
    __shared__ float wgt_s[BM];

    const int tid = threadIdx.x;
    const int wave = tid >> 6, lane = tid & 63;

    if (tid < BM) {
        int r = off + min(m0 + tid, cnt - 1);
        tok_s[tid] = (MODE == 0) ? token_list[r] : r;
        wgt_s[tid] = wgt_list[r];
    }
    __syncthreads();

    // staging addresses (1KB per instr = 16 rows x 64B)
    const char* Abytes = (const char*)Abase;
    const char* Bbytes = (const char*)(Bt + (size_t)e * NDIM * K);
    const int rl = lane >> 2;                       // row within instr (0..15)
    const int chk = (lane & 3) ^ (rl & 3);          // global chunk fetched
    uint64_t ga[NIA], gb[2];
    uint32_t la[NIA], lb[2];
#pragma unroll
    for (int j = 0; j < NIA; j++) {
        int rowA = (wave * NIA + j) * 16 + rl;
        ga[j] = (uint64_t)(uintptr_t)(Abytes + ((size_t)tok_s[rowA] * AST + chk * 8) * 2);
        la[j] = (wave * NIA + j) * 512;             // element offset
    }
#pragma unroll
    for (int j = 0; j < 2; j++) {
        int rowB = n0 + (wave * 2 + j) * 16 + rl;
        gb[j] = (uint64_t)(uintptr_t)(Bbytes + ((size_t)rowB * K + chk * 8) * 2);
        lb[j] = (wave * 2 + j) * 512;
    }

    f32x4 acc[MI][4];
#pragma unroll
    for (int i = 0; i < MI; i++)
#pragma unroll
        for (int j = 0; j < 4; j++) acc[i][j] = (f32x4){0.f, 0.f, 0.f, 0.f};

    const int wr = wave >> 1, wc = wave & 1;
    const int lane15 = lane & 15, quad = lane >> 4;

    // prologue: stage tile 0 into buffer 0
#pragma unroll
    for (int j = 0; j < NIA; j++) {
        gl_lds16((const void*)(uintptr_t)ga[j], (void*)(As + la[j]));
        ga[j] += 64;
    }
#pragma unroll
    for (int j = 0; j < 2; j++) {
        gl_lds16((const void*)(uintptr_t)gb[j], (void*)(Bs + lb[j]));
        gb[j] += 64;
    }
    __syncthreads();

    for (int kt = 0; kt < NK; kt++) {
        const int cur = kt & 1;
        if (kt + 1 < NK) {  // stage next tile into alt buffer (async)
            const int nxt = cur ^ 1;
#pragma unroll
            for (int j = 0; j < NIA; j++) {
                gl_lds16((const void*)(uintptr_t)ga[j], (void*)(As + nxt * ABUF + la[j]));
                ga[j] += 64;
            }
#pragma unroll
            for (int j = 0; j < 2; j++) {
                gl_lds16((const void*)(uintptr_t)gb[j], (void*)(Bs + nxt * BBUF + lb[j]));
                gb[j] += 64;
            }
        }
        const __bf16* Ab = As + cur * ABUF;
        const __bf16* Bb = Bs + cur * BBUF;
        bf16x8 a[MI], b[4];
#pragma unroll
        for (int i = 0; i < MI; i++) {
            int row = wr * (BM / 2) + i * 16 + lane15;
            a[i] = *(const bf16x8*)&Ab[row * 32 + ((quad ^ (row & 3)) * 8)];
        }
#pragma unroll
        for (int j = 0; j < 4; j++) {
            int row = wc * 64 + j * 16 + lane15;
            b[j] = *(const bf16x8*)&Bb[row * 32 + ((quad ^ (row & 3)) * 8)];
        }
#pragma unroll
        for (int i = 0; i < MI; i++)
#pragma unroll
            for (int j = 0; j < 4; j++)
                acc[i][j] = __builtin_amdgcn_mfma_f32_16x16x32_bf16(a[i], b[j], acc[i][j], 0, 0, 0);
        __syncthreads();  // drains next tile's async loads + frees cur buffer
    }

    // epilogue: C/D layout col=lane&15, row=quad*4+reg
#pragma unroll
    for (int j = 0; j < 4; j++) {
        int col = n0 + wc * 64 + j * 16 + lane15;
        float bv = f32 ? ((const float*)bias)[(size_t)e * NDIM + col]
                       : b2f(((const unsigned short*)bias)[(size_t)e * NDIM + col]);
#pragma unroll
        for (int i = 0; i < MI; i++) {
#pragma unroll
            for (int r = 0; r < 4; r++) {
                int rowl = wr * (BM / 2) + i * 16 + quad * 4 + r;
                if (m0 + rowl < cnt) {
                    float v = acc[i][j][r] + bv;
                    if (MODE == 0) {
                        act_out[(size_t)(off + m0 + rowl) * F_DIM + col] = f2b(gelu_f(v));
                    } else {
                        y_out[(size_t)(off + m0 + rowl) * H_DIM + col] = f2b(v * wgt_s[rowl]);
                    }
                }
            }
        }
    }
}

// ---- combine: out[t] = y[slot0] + y[slot1]; write bf16 or fp32 ------------
__global__ __launch_bounds__(256) void combine_kernel(
    const unsigned short* __restrict__ y, const int* __restrict__ assign_row,
    void* __restrict__ out, const int* __restrict__ flag) {
    bool f32 = (*flag != 0);
    int t = blockIdx.x;
    int r0 = assign_row[t * 2], r1 = assign_row[t * 2 + 1];
    ushort4 a = ((const ushort4*)(y + (size_t)r0 * H_DIM))[threadIdx.x];
    ushort4 b = ((const ushort4*)(y + (size_t)r1 * H_DIM))[threadIdx.x];
    float s0 = b2f(a.x) + b2f(b.x), s1 = b2f(a.y) + b2f(b.y);
    float s2 = b2f(a.z) + b2f(b.z), s3 = b2f(a.w) + b2f(b.w);
    if (f32) {
        float4 o = {s0, s1, s2, s3};
        ((float4*)out)[(size_t)t * (H_DIM / 4) + threadIdx.x] = o;
    } else {
        ushort4 o;
        o.x = f2b(s0); o.y = f2b(s1); o.z = f2b(s2); o.w = f2b(s3);
        ((ushort4*)((unsigned short*)out + (size_t)t * H_DIM))[threadIdx.x] = o;
    }
}

extern "C" void kernel_launch(void* const* d_in, const int* in_sizes, int n_in,
                              void* d_out, int out_size, void* d_ws, size_t ws_size,
                              hipStream_t stream) {
    const void* hs = d_in[0];
    const void* rw = d_in[1];
    const void* rb = d_in[2];
    const void* w1 = d_in[3];
    const void* b1 = d_in[4];
    const void* w2 = d_in[5];
    const void* b2 = d_in[6];

    char* ws = (char*)d_ws;
    size_t o = 0;
    auto alloc = [&](size_t bytes) {
        char* p = ws + o; o += (bytes + 255) & ~(size_t)255; return p;
    };
    unsigned short* wt   = (unsigned short*)alloc((size_t)NE * F_DIM * H_DIM * 2);  // 64 MB (reused)
    unsigned short* act  = (unsigned short*)alloc((size_t)NA * F_DIM * 2);          // 64 MB
    unsigned short* yb   = (unsigned short*)alloc((size_t)NA * H_DIM * 2);          // 16 MB
    unsigned short* hsb  = (unsigned short*)alloc((size_t)T_TOKENS * H_DIM * 2);    //  8 MB
    int*   top_i      = (int*)alloc(NA * 4);
    float* top_w      = (float*)alloc(NA * 4);
    int*   token_list = (int*)alloc(NA * 4);
    float* wgt_list   = (float*)alloc(NA * 4);
    int*   assign_row = (int*)alloc(NA * 4);
    int*   counts     = (int*)alloc(64);
    int*   offsets    = (int*)alloc(64);
    int*   flag       = (int*)alloc(64);
    (void)ws_size; (void)in_sizes; (void)n_in; (void)out_size;

    probe_kernel<<<1, 64, 0, stream>>>((const unsigned short*)hs, flag);
    router_kernel<<<T_TOKENS / 4, 256, 0, stream>>>(hs, rw, rb, flag, top_i, top_w, hsb);
    assign_kernel<<<1, 256, 0, stream>>>(top_i, top_w, token_list, wgt_list,
                                         assign_row, counts, offsets);
    transpose_kernel<<<dim3(F_DIM / 64, H_DIM / 64, NE), 256, 0, stream>>>(
        w1, wt, H_DIM, F_DIM, flag);
    gemm_kernel<0><<<dim3(F_DIM / 128, T_TOKENS / 128, NE), 256, 0, stream>>>(
        hsb, wt, b1, flag, token_list, wgt_list, counts, offsets, act, nullptr);
    transpose_kernel<<<dim3(H_DIM / 64, F_DIM / 64, NE), 256, 0, stream>>>(
        w2, wt, F_DIM, H_DIM, flag);
    gemm_kernel<1><<<dim3(H_DIM / 128, T_TOKENS / 64, NE), 256, 0, stream>>>(
        act, wt, b2, flag, token_list, wgt_list, counts, offsets, nullptr, yb);
    combine_kernel<<<T_TOKENS, 256, 0, stream>>>(yb, assign_row, d_out, flag);
}